// Round 15
// baseline (258.671 us; speedup 1.0000x reference)
//
#include <hip/hip_runtime.h>
#include <hip/hip_fp16.h>
#include <math.h>

#define HD 64
#define HNUM 128
#define NMLP 2
#define BSH 8              // 256 dst-nodes per bucket
#define MAXNB 512
#define EPB 4096           // edges per k_bin block (16/thread)

typedef unsigned int uint_t;
typedef unsigned short ushort_t;
typedef _Float16 h8 __attribute__((ext_vector_type(8)));
typedef float vf4 __attribute__((ext_vector_type(4)));

union H8U { h8 v; uint_t u[4]; };

__device__ __forceinline__ float lrelu(float x){ return fmaxf(x, 0.2f*x); }

__device__ __forceinline__ float cvt_h(uint_t wv, uint_t sh){
    __half_raw hr; hr.x = (ushort_t)(wv >> sh);
    return __half2float((__half)hr);
}
__device__ __forceinline__ uint_t pk2(float a, float b){
    return (uint_t)__half_as_ushort(__float2half_rn(a)) |
           ((uint_t)__half_as_ushort(__float2half_rn(b)) << 16);
}

// ---------------- CSR build: bucketed counting sort (packed 4B records) ----------------
__global__ __launch_bounds__(256) void k_bcnt(const int* __restrict__ dst, int* __restrict__ gb,
                                              int E, int NB){
    __shared__ int h[MAXNB];
    int t = threadIdx.x;
    for(int i=t;i<NB;i+=256) h[i] = 0;
    __syncthreads();
    for(int e = blockIdx.x*256 + t; e < E; e += gridDim.x*256)
        atomicAdd(&h[dst[e]>>BSH], 1);
    __syncthreads();
    for(int i=t;i<NB;i+=256) if(h[i]) atomicAdd(&gb[i], h[i]);
}

__global__ __launch_bounds__(512) void k_bscan(const int* __restrict__ gb, int* __restrict__ bbase,
                                               int* __restrict__ gcur, int NB){
    __shared__ int s[512];
    int t = threadIdx.x;
    int v = (t < NB) ? gb[t] : 0;
    s[t] = v; __syncthreads();
    for(int o=1;o<512;o<<=1){
        int u = (t >= o) ? s[t-o] : 0;
        __syncthreads();
        s[t] += u;
        __syncthreads();
    }
    if(t < NB){ int ex = s[t] - v; bbase[t] = ex; gcur[t] = ex; }
}

// bin edges as packed (src<<8)|(dst&255); 16 edges/thread to coarsen bucket claims
__global__ __launch_bounds__(256) void k_bin(const int* __restrict__ src, const int* __restrict__ dst,
                                             int* __restrict__ gcur, uint_t* __restrict__ bdata,
                                             int E, int NB){
    __shared__ int cnt[MAXNB];
    __shared__ int base[MAXNB];
    int t = threadIdx.x;
    for(int i=t;i<NB;i+=256) cnt[i] = 0;
    __syncthreads();
    int s0 = blockIdx.x*EPB;
    uint_t pk[16]; int bk[16], off[16];
    #pragma unroll
    for(int i=0;i<16;i++){
        int e = s0 + i*256 + t;
        if(e < E){
            int sv = src[e], dv = dst[e];
            pk[i]  = ((uint_t)sv << 8) | (uint_t)(dv & 255);
            bk[i]  = dv >> BSH;
            off[i] = atomicAdd(&cnt[bk[i]], 1);
        }
    }
    __syncthreads();
    for(int i=t;i<NB;i+=256) base[i] = cnt[i] ? atomicAdd(&gcur[i], cnt[i]) : 0;
    __syncthreads();
    #pragma unroll
    for(int i=0;i<16;i++){
        int e = s0 + i*256 + t;
        if(e < E) bdata[base[bk[i]] + off[i]] = pk[i];
    }
}

// fused per-bucket: LDS hist -> LDS scan -> rowptr slice -> LDS-cursor scatter
__global__ __launch_bounds__(256) void k_bfuse(const uint_t* __restrict__ bdata, const int* __restrict__ bbase,
                                               const int* __restrict__ gb, int* __restrict__ rp,
                                               int* __restrict__ col, int n, int NB, int E){
    __shared__ int h[256];
    __shared__ int sc[256];
    int b = blockIdx.x, t = threadIdx.x;
    int beg = bbase[b], cnt = gb[b];
    h[t] = 0; __syncthreads();
    for(int i=t;i<cnt;i+=256) atomicAdd(&h[bdata[beg+i] & 255], 1);
    __syncthreads();
    int v = h[t];
    sc[t] = v; __syncthreads();
    for(int o=1;o<256;o<<=1){
        int u = (t >= o) ? sc[t-o] : 0;
        __syncthreads();
        sc[t] += u;
        __syncthreads();
    }
    int excl = sc[t] - v;
    int node = (b<<BSH) + t;
    if(node < n) rp[node] = beg + excl;
    if(b == NB-1 && t == 255) rp[n] = E;
    __syncthreads();
    sc[t] = excl;           // per-node local cursor
    __syncthreads();
    for(int i=t;i<cnt;i+=256){
        uint_t e = bdata[beg+i];
        int pos = atomicAdd(&sc[e & 255], 1);
        col[beg + pos] = (int)(e >> 8);
    }
}

// ---------------- vn-group build: counting sort of nodes by hb ----------------
__global__ __launch_bounds__(256) void k_vcnt(const int* __restrict__ hb, int* __restrict__ vcnt, int n){
    __shared__ int h[HNUM];
    int t = threadIdx.x;
    if(t < HNUM) h[t] = 0;
    __syncthreads();
    for(int i = blockIdx.x*256 + t; i < n; i += gridDim.x*256) atomicAdd(&h[hb[i]], 1);
    __syncthreads();
    if(t < HNUM && h[t]) atomicAdd(&vcnt[t], h[t]);
}

__global__ __launch_bounds__(128) void k_vscan(const int* __restrict__ vcnt, int* __restrict__ vrp,
                                               int* __restrict__ vcur, int n){
    __shared__ int s[HNUM];
    int t = threadIdx.x;
    int v = vcnt[t];
    s[t] = v; __syncthreads();
    for(int o=1;o<HNUM;o<<=1){
        int u = (t >= o) ? s[t-o] : 0;
        __syncthreads();
        s[t] += u;
        __syncthreads();
    }
    int ex = s[t] - v;
    vrp[t] = ex; vcur[t] = ex;
    if(t == HNUM-1) vrp[HNUM] = n;
}

__global__ __launch_bounds__(256) void k_vbin(const int* __restrict__ hb, int* __restrict__ vcur,
                                              int* __restrict__ perm, int n){
    __shared__ int cnt[HNUM];
    __shared__ int base[HNUM];
    int t = threadIdx.x;
    if(t < HNUM) cnt[t] = 0;
    __syncthreads();
    int s0 = blockIdx.x*2048;
    int hv[8], off[8];
    #pragma unroll
    for(int i=0;i<8;i++){
        int nd = s0 + i*256 + t;
        if(nd < n){ hv[i] = hb[nd]; off[i] = atomicAdd(&cnt[hv[i]], 1); }
    }
    __syncthreads();
    if(t < HNUM) base[t] = cnt[t] ? atomicAdd(&vcur[t], cnt[t]) : 0;
    __syncthreads();
    #pragma unroll
    for(int i=0;i<8;i++){
        int nd = s0 + i*256 + t;
        if(nd < n) perm[base[hv[i]] + off[i]] = nd;
    }
}

// ---------------- degree sort: counting sort of dsts by degree (256 bins) ----------------
__global__ __launch_bounds__(256) void k_dcnt(const int* __restrict__ rp, int* __restrict__ dcnt, int n){
    __shared__ int h[256];
    int t = threadIdx.x;
    h[t] = 0;
    __syncthreads();
    for(int i = blockIdx.x*256 + t; i < n; i += gridDim.x*256){
        int d = min(rp[i+1] - rp[i], 255);
        atomicAdd(&h[d], 1);
    }
    __syncthreads();
    if(h[t]) atomicAdd(&dcnt[t], h[t]);
}

__global__ __launch_bounds__(256) void k_dscan(const int* __restrict__ dcnt, int* __restrict__ dcur){
    __shared__ int s[256];
    int t = threadIdx.x;
    int v = dcnt[t];
    s[t] = v; __syncthreads();
    for(int o=1;o<256;o<<=1){
        int u = (t >= o) ? s[t-o] : 0;
        __syncthreads();
        s[t] += u;
        __syncthreads();
    }
    dcur[t] = s[t] - v;
}

__global__ __launch_bounds__(256) void k_dbin(const int* __restrict__ rp, int* __restrict__ dcur,
                                              int* __restrict__ dperm, int n){
    __shared__ int cnt[256];
    __shared__ int base[256];
    int t = threadIdx.x;
    cnt[t] = 0;
    __syncthreads();
    int s0 = blockIdx.x*2048;
    int dv[8], off[8];
    #pragma unroll
    for(int i=0;i<8;i++){
        int nd = s0 + i*256 + t;
        if(nd < n){
            dv[i] = min(rp[nd+1] - rp[nd], 255);
            off[i] = atomicAdd(&cnt[dv[i]], 1);
        }
    }
    __syncthreads();
    base[t] = cnt[t] ? atomicAdd(&dcur[t], cnt[t]) : 0;
    __syncthreads();
    #pragma unroll
    for(int i=0;i<8;i++){
        int nd = s0 + i*256 + t;
        if(nd < n) dperm[base[dv[i]] + off[i]] = nd;
    }
}

// ---------------- one-time weight fragment pack + W@a precompute ----------------
__global__ __launch_bounds__(256) void k_wcvt(
    const float* __restrict__ W0, const float* __restrict__ as0, const float* __restrict__ ad0,
    const float* __restrict__ Wl, const float* __restrict__ asl, const float* __restrict__ adl,
    uint4* __restrict__ Wf3, float* __restrict__ waf3)
{
    __shared__ float wa[2][64];
    int L = blockIdx.x, t = threadIdx.x;
    const float* W  = (L==0) ? W0  : Wl  + (L-1)*HD*HD;
    const float* as = (L==0) ? as0 : asl + (L-1)*HD;
    const float* ad = (L==0) ? ad0 : adl + (L-1)*HD;
    if(t < 128){
        int sd = t>>6, k = t&63;
        const float* av = sd ? ad : as;
        float acc = 0.f;
        for(int c=0;c<HD;c++) acc = fmaf(W[k*HD+c], av[c], acc);
        wa[sd][k] = acc;
    }
    __syncthreads();
    for(int it = t; it < 512; it += 256){
        int lane = it&63, s = (it>>6)&1, tile = it>>7;
        int g = lane>>4, m = lane&15, c = tile*16 + m;
        ushort_t h[8];
        #pragma unroll
        for(int i=0;i<8;i++){
            int k = s*32 + g*4 + (i&3) + 16*(i>>2);
            h[i] = __half_as_ushort(__float2half_rn(W[k*HD + c]));
        }
        uint4 q;
        q.x = (uint_t)h[0] | ((uint_t)h[1]<<16);
        q.y = (uint_t)h[2] | ((uint_t)h[3]<<16);
        q.z = (uint_t)h[4] | ((uint_t)h[5]<<16);
        q.w = (uint_t)h[6] | ((uint_t)h[7]<<16);
        Wf3[(size_t)L*512 + (tile*2+s)*64 + lane] = q;
    }
    if(t < 128){
        int lane = t&63, sd = t>>6, g = lane>>4;
        #pragma unroll
        for(int j4=0;j4<4;j4++){
            float v[4];
            #pragma unroll
            for(int e=0;e<4;e++){
                int j = j4*4 + e;
                int k = (j>>3)*32 + g*4 + (j&3) + 16*((j>>2)&1);
                v[e] = wa[sd][k];
            }
            float* dstp = waf3 + ((size_t)L*8 + sd*4 + j4)*64*4 + lane*4;
            dstp[0]=v[0]; dstp[1]=v[1]; dstp[2]=v[2]; dstp[3]=v[3];
        }
    }
}

// ---------------- MFMA GEMM: 16 rows x 64 cols per wave ----------------
// Hw pair-layout: row dword w holds fp16 cols (32*(w>>4)+(w&15), same+16)
__global__ __launch_bounds__(256) void k_gemm(
    const float* __restrict__ IN, const float* __restrict__ addrow,
    const float* __restrict__ addtab, const int* __restrict__ hb,
    const uint4* __restrict__ Wf, const float* __restrict__ waf,
    uint_t* __restrict__ Hw, float* __restrict__ AS, float* __restrict__ AD,
    int n)
{
    __shared__ ushort_t sx[4][1024];
    int t = threadIdx.x, lane = t&63, wv = t>>6;
    int g = lane>>4, m = lane&15;
    ushort_t* sb = sx[wv];

    H8U B[8];
    #pragma unroll
    for(int f=0; f<8; f++){
        uint4 q = Wf[f*64 + lane];
        B[f].u[0]=q.x; B[f].u[1]=q.y; B[f].u[2]=q.z; B[f].u[3]=q.w;
    }
    vf4 wS[4], wD[4];
    #pragma unroll
    for(int j4=0;j4<4;j4++){
        const float* ps = waf + ((size_t)0*4 + j4)*256 + lane*4;
        const float* pd = waf + ((size_t)1*4 + j4)*256 + lane*4;
        wS[j4] = vf4{ps[0],ps[1],ps[2],ps[3]};
        wD[j4] = vf4{pd[0],pd[1],pd[2],pd[3]};
    }
    float ar0=0,ar1=0,ar2=0,ar3=0;
    if(addrow){
        const float* a = &addrow[m*4];
        ar0=a[0]; ar1=a[1]; ar2=a[2]; ar3=a[3];
    }

    int ntiles = (n + 15) >> 4;
    int wgid = (blockIdx.x*256 + t) >> 6;
    int nw = gridDim.x*4;
    for(int tile = wgid; tile < ntiles; tile += nw){
        int rb = tile*16;
        #pragma unroll
        for(int p=0;p<4;p++){
            int row = p*4 + g;
            int rowc = min(rb + row, n-1);
            float4 x4 = *(const float4*)&IN[(size_t)rowc*HD + m*4];
            if(addrow){ x4.x+=ar0; x4.y+=ar1; x4.z+=ar2; x4.w+=ar3; }
            if(addtab){
                int b = hb[rowc];
                float4 a4 = *(const float4*)&addtab[b*HD + m*4];
                x4.x+=a4.x; x4.y+=a4.y; x4.z+=a4.z; x4.w+=a4.w;
            }
            uint2 pq; pq.x = pk2(x4.x, x4.y); pq.y = pk2(x4.z, x4.w);
            int idx = (row*64 + m*4) ^ ((row&7)<<3);
            *(uint2*)&sb[idx] = pq;
        }
        int xr = (m&7)<<3;
        H8U A0, A1;
        {
            uint2 c0 = *(uint2*)&sb[(m*64 +  0 + g*4) ^ xr];
            uint2 c1 = *(uint2*)&sb[(m*64 + 16 + g*4) ^ xr];
            A0.u[0]=c0.x; A0.u[1]=c0.y; A0.u[2]=c1.x; A0.u[3]=c1.y;
            uint2 c2 = *(uint2*)&sb[(m*64 + 32 + g*4) ^ xr];
            uint2 c3 = *(uint2*)&sb[(m*64 + 48 + g*4) ^ xr];
            A1.u[0]=c2.x; A1.u[1]=c2.y; A1.u[2]=c3.x; A1.u[3]=c3.y;
        }
        float t1 = 0.f, t2 = 0.f;
        #pragma unroll
        for(int i=0;i<8;i++){
            float xv = (float)A0.v[i];
            t1 = fmaf(xv, wS[i>>2][i&3], t1);
            t2 = fmaf(xv, wD[i>>2][i&3], t2);
        }
        #pragma unroll
        for(int i=0;i<8;i++){
            float xv = (float)A1.v[i];
            t1 = fmaf(xv, wS[2+(i>>2)][i&3], t1);
            t2 = fmaf(xv, wD[2+(i>>2)][i&3], t2);
        }
        t1 += __shfl_xor(t1, 16, 64); t1 += __shfl_xor(t1, 32, 64);
        t2 += __shfl_xor(t2, 16, 64); t2 += __shfl_xor(t2, 32, 64);
        if(lane < 16 && rb + lane < n){ AS[rb+lane] = t1; AD[rb+lane] = t2; }
        vf4 z = {0.f,0.f,0.f,0.f};
        vf4 a0 = __builtin_amdgcn_mfma_f32_16x16x32_f16(A0.v, B[0].v, z, 0,0,0);
        a0     = __builtin_amdgcn_mfma_f32_16x16x32_f16(A1.v, B[1].v, a0, 0,0,0);
        vf4 a1 = __builtin_amdgcn_mfma_f32_16x16x32_f16(A0.v, B[2].v, z, 0,0,0);
        a1     = __builtin_amdgcn_mfma_f32_16x16x32_f16(A1.v, B[3].v, a1, 0,0,0);
        vf4 a2 = __builtin_amdgcn_mfma_f32_16x16x32_f16(A0.v, B[4].v, z, 0,0,0);
        a2     = __builtin_amdgcn_mfma_f32_16x16x32_f16(A1.v, B[5].v, a2, 0,0,0);
        vf4 a3 = __builtin_amdgcn_mfma_f32_16x16x32_f16(A0.v, B[6].v, z, 0,0,0);
        a3     = __builtin_amdgcn_mfma_f32_16x16x32_f16(A1.v, B[7].v, a3, 0,0,0);
        #pragma unroll
        for(int rr=0;rr<4;rr++){
            int row = rb + g*4 + rr;
            if(row < n){
                Hw[(size_t)row*32 + m]      = pk2(a0[rr], a1[rr]);
                Hw[(size_t)row*32 + 16 + m] = pk2(a2[rr], a3[rr]);
            }
        }
    }
}

// ---------------- GAT aggregate: quarter-wave per dst, degree-sorted order ----------------
__global__ __launch_bounds__(256) void k_agg(
    const uint_t* __restrict__ Hb, const float* __restrict__ AS, const float* __restrict__ AD,
    const int* __restrict__ rp, const int* __restrict__ col, const int* __restrict__ dperm,
    const float* __restrict__ bias, float* __restrict__ OUT, int n)
{
    int t = threadIdx.x, lane = t & 63;
    int p = lane & 15;          // position within quarter
    int qb = lane & 48;         // quarter base lane (0,16,32,48)
    int w0 = 2*p;
    int c00 = 32*(w0>>4)+(w0&15), c01 = c00+16;
    int c10 = c00+1, c11 = c00+17;
    float b00 = bias[c00], b01 = bias[c01], b10 = bias[c10], b11 = bias[c11];
    int wv  = (blockIdx.x*256 + t) >> 6;
    int nwv = gridDim.x*4;
    for(int base = wv*4; base < n; base += nwv*4){
        int pos = base + (qb>>4);
        int dq = dperm[min(pos, n-1)];
        float ad = AD[dq];
        float wself = __expf(lrelu(AS[dq] + ad));
        uint2 hd = *(const uint2*)&Hb[(size_t)dq*32 + w0];
        float4 acc;
        acc.x = cvt_h(hd.x,0)*wself; acc.y = cvt_h(hd.x,16)*wself;
        acc.z = cvt_h(hd.y,0)*wself; acc.w = cvt_h(hd.y,16)*wself;
        float sacc = 0.f;
        int beg = rp[dq], end = rp[dq+1];
        int cnt = end - beg;
        int nit = (cnt + 15) >> 4;
        nit = max(nit, __shfl_xor(nit, 16, 64));
        nit = max(nit, __shfl_xor(nit, 32, 64));
        for(int it = 0; it < nit; it++){
            int j = beg + it*16 + p;
            bool valid = j < end;
            int sj = dq;
            if(cnt > 0) sj = col[valid ? j : end - 1];
            float wj = 0.f;
            if(valid) wj = __expf(lrelu(AS[sj] + ad));
            sacc += wj;
            int ccnt = cnt - it*16;
            ccnt = ccnt < 0 ? 0 : (ccnt > 16 ? 16 : ccnt);
            int emax = ccnt;
            emax = max(emax, __shfl_xor(emax, 16, 64));
            emax = max(emax, __shfl_xor(emax, 32, 64));
            int e = 0;
            for(; e + 4 <= emax; e += 4){
                float wq0 = __shfl(wj, qb+e,   64);
                float wq1 = __shfl(wj, qb+e+1, 64);
                float wq2 = __shfl(wj, qb+e+2, 64);
                float wq3 = __shfl(wj, qb+e+3, 64);
                int   sq0 = __shfl(sj, qb+e,   64);
                int   sq1 = __shfl(sj, qb+e+1, 64);
                int   sq2 = __shfl(sj, qb+e+2, 64);
                int   sq3 = __shfl(sj, qb+e+3, 64);
                uint2 v0 = *(const uint2*)&Hb[(size_t)sq0*32 + w0];
                uint2 v1 = *(const uint2*)&Hb[(size_t)sq1*32 + w0];
                uint2 v2 = *(const uint2*)&Hb[(size_t)sq2*32 + w0];
                uint2 v3 = *(const uint2*)&Hb[(size_t)sq3*32 + w0];
                acc.x = fmaf(wq0, cvt_h(v0.x,0),  acc.x);
                acc.y = fmaf(wq0, cvt_h(v0.x,16), acc.y);
                acc.z = fmaf(wq0, cvt_h(v0.y,0),  acc.z);
                acc.w = fmaf(wq0, cvt_h(v0.y,16), acc.w);
                acc.x = fmaf(wq1, cvt_h(v1.x,0),  acc.x);
                acc.y = fmaf(wq1, cvt_h(v1.x,16), acc.y);
                acc.z = fmaf(wq1, cvt_h(v1.y,0),  acc.z);
                acc.w = fmaf(wq1, cvt_h(v1.y,16), acc.w);
                acc.x = fmaf(wq2, cvt_h(v2.x,0),  acc.x);
                acc.y = fmaf(wq2, cvt_h(v2.x,16), acc.y);
                acc.z = fmaf(wq2, cvt_h(v2.y,0),  acc.z);
                acc.w = fmaf(wq2, cvt_h(v2.y,16), acc.w);
                acc.x = fmaf(wq3, cvt_h(v3.x,0),  acc.x);
                acc.y = fmaf(wq3, cvt_h(v3.x,16), acc.y);
                acc.z = fmaf(wq3, cvt_h(v3.y,0),  acc.z);
                acc.w = fmaf(wq3, cvt_h(v3.y,16), acc.w);
            }
            for(; e < emax; e++){
                float wq = __shfl(wj, qb+e, 64);
                int   sq = __shfl(sj, qb+e, 64);
                uint2 v = *(const uint2*)&Hb[(size_t)sq*32 + w0];
                acc.x = fmaf(wq, cvt_h(v.x,0),  acc.x);
                acc.y = fmaf(wq, cvt_h(v.x,16), acc.y);
                acc.z = fmaf(wq, cvt_h(v.y,0),  acc.z);
                acc.w = fmaf(wq, cvt_h(v.y,16), acc.w);
            }
        }
        sacc += __shfl_xor(sacc, 1, 64);
        sacc += __shfl_xor(sacc, 2, 64);
        sacc += __shfl_xor(sacc, 4, 64);
        sacc += __shfl_xor(sacc, 8, 64);
        float s = wself + sacc;
        float inv = 1.f/(s + 1e-16f);
        if(pos < n){
            OUT[(size_t)dq*HD + c00] = fmaf(acc.x, inv, b00);
            OUT[(size_t)dq*HD + c01] = fmaf(acc.y, inv, b01);
            OUT[(size_t)dq*HD + c10] = fmaf(acc.z, inv, b10);
            OUT[(size_t)dq*HD + c11] = fmaf(acc.w, inv, b11);
        }
    }
}

// ---------------- vn segment sum: hb-grouped, pure register accumulation ----------------
__global__ __launch_bounds__(256) void k_vsum(const float* __restrict__ OUT, const int* __restrict__ perm,
                                              const int* __restrict__ vrp, float* __restrict__ vnS){
    int t = threadIdx.x, lane = t & 63, w = t >> 6;
    int g = blockIdx.x >> 3, sub = blockIdx.x & 7;
    int wig = sub*4 + w;                  // wave index in group: 0..31
    int beg = vrp[g], end = vrp[g+1];
    float a0=0.f, a1=0.f, a2=0.f, a3=0.f;
    int i = beg + wig;
    for(; i + 96 < end; i += 128){
        int p0 = perm[i], p1 = perm[i+32], p2 = perm[i+64], p3 = perm[i+96];
        a0 += OUT[(size_t)p0*HD + lane];
        a1 += OUT[(size_t)p1*HD + lane];
        a2 += OUT[(size_t)p2*HD + lane];
        a3 += OUT[(size_t)p3*HD + lane];
    }
    for(; i < end; i += 32) a0 += OUT[(size_t)perm[i]*HD + lane];
    float a = (a0+a1)+(a2+a3);
    unsafeAtomicAdd(&vnS[g*HD + lane], a);   // 32 contenders per address
}

// ---------------- vn update: one wave per vn row; LDS-broadcast MLPs ----------------
__global__ __launch_bounds__(64) void k_vn(
    const float* __restrict__ vnS, const float* __restrict__ vne,
    const float* __restrict__ W1, const float* __restrict__ B1,
    const float* __restrict__ W2, const float* __restrict__ B2,
    float* __restrict__ vnD)
{
    __shared__ float sx[HD];
    int lane = threadIdx.x;
    int r = blockIdx.x;                 // vn row 0..HNUM-1
    float ve = vne[lane];
    float a = vnS[r*HD + lane] + ve + ve;   // segsum + vn_direct0 + vn_root0
    for(int j=0;j<NMLP;j++){
        const float* w1 = W1 + j*HD*HD; const float* b1 = B1 + j*HD;
        const float* w2 = W2 + j*HD*HD; const float* b2 = B2 + j*HD;
        __syncthreads();
        sx[lane] = a;
        __syncthreads();
        float t = b1[lane];
        #pragma unroll
        for(int in=0;in<HD;in++) t = fmaf(sx[in], w1[in*HD + lane], t);
        t = fmaxf(t, 0.f);
        __syncthreads();
        sx[lane] = t;
        __syncthreads();
        float u = b2[lane];
        #pragma unroll
        for(int in=0;in<HD;in++) u = fmaf(sx[in], w2[in*HD + lane], u);
        a = fmaxf(u, 0.f);
    }
    vnD[r*HD + lane] = a;
}

extern "C" void kernel_launch(void* const* d_in, const int* in_sizes, int n_in,
                              void* d_out, int out_size, void* d_ws, size_t ws_size,
                              hipStream_t stream)
{
    const float* x   = (const float*)d_in[0];
    const int*   ei  = (const int*)d_in[1];
    const int*   hb  = (const int*)d_in[2];
    const float* W0  = (const float*)d_in[5];
    const float* as0 = (const float*)d_in[6];
    const float* ad0 = (const float*)d_in[7];
    const float* b0  = (const float*)d_in[8];
    const float* Wl  = (const float*)d_in[9];
    const float* asl = (const float*)d_in[10];
    const float* adl = (const float*)d_in[11];
    const float* bl  = (const float*)d_in[12];
    const float* vne = (const float*)d_in[13];
    const float* mW1 = (const float*)d_in[14];
    const float* mb1 = (const float*)d_in[15];
    const float* mW2 = (const float*)d_in[16];
    const float* mb2 = (const float*)d_in[17];

    int N = in_sizes[0]/HD;
    int E = in_sizes[1]/2;
    const int* src = ei;
    const int* dst = ei + E;
    int NB = (N + (1<<BSH) - 1) >> BSH;

    char* p = (char*)d_ws;
    float* f_h   = (float*)p; p += (size_t)N*HD*4;   // fp16 H (lower half) + CSR alias
    float* f_as  = (float*)p; p += (size_t)N*4;
    float* f_ad  = (float*)p; p += (size_t)N*4;
    float* f_vnD = (float*)p; p += HNUM*HD*4;
    float* f_vnS = (float*)p; p += HNUM*HD*4;        // zeroed with i_vcnt+i_dcnt below
    int*   i_vcnt= (int*)p;   p += HNUM*4;
    int*   i_dcnt= (int*)p;   p += 256*4;
    int*   i_vrp = (int*)p;   p += (HNUM+1)*4;
    int*   i_vcur= (int*)p;   p += HNUM*4;
    int*   i_dcur= (int*)p;   p += 256*4;
    int*   i_perm= (int*)p;   p += (size_t)N*4;
    int*   i_dperm=(int*)p;   p += (size_t)N*4;
    int*   i_rp  = (int*)p;   p += (size_t)(N+1)*4;
    int*   i_gb  = (int*)p;   p += MAXNB*4;
    int*   i_bb  = (int*)p;   p += MAXNB*4;
    int*   i_gc  = (int*)p;   p += MAXNB*4;
    int*   i_col = (int*)p;   p += (size_t)E*4;
    uint4* Wf3   = (uint4*)p; p += 3*512*16;
    float* waf3  = (float*)p; p += 3*8*64*4*4;
    uint_t* bdata= (uint_t*)f_h;                      // alias: f_h not live during CSR build
    uint_t* Hw   = (uint_t*)f_h;                      // N*32 dwords = lower 12.8 MB

    float* outb = (float*)d_out;

    // one-time weight pack (3 blocks = 3 layers)
    k_wcvt<<<3, 256, 0, stream>>>(W0, as0, ad0, Wl, asl, adl, Wf3, waf3);

    hipMemsetAsync(i_gb, 0, MAXNB*4, stream);
    hipMemsetAsync(f_vnS, 0, HNUM*HD*4 + HNUM*4 + 256*4, stream);   // vnS + vcnt + dcnt
    // edge CSR
    k_bcnt <<<512, 256, 0, stream>>>(dst, i_gb, E, NB);
    k_bscan<<<1, 512, 0, stream>>>(i_gb, i_bb, i_gc, NB);
    k_bin  <<<(E+EPB-1)/EPB, 256, 0, stream>>>(src, dst, i_gc, bdata, E, NB);
    k_bfuse<<<NB, 256, 0, stream>>>(bdata, i_bb, i_gb, i_rp, i_col, N, NB, E);
    // vn-group permutation (counting sort of nodes by hb)
    k_vcnt <<<128, 256, 0, stream>>>(hb, i_vcnt, N);
    k_vscan<<<1, 128, 0, stream>>>(i_vcnt, i_vrp, i_vcur, N);
    k_vbin <<<(N+2047)/2048, 256, 0, stream>>>(hb, i_vcur, i_perm, N);
    // degree permutation (counting sort of dsts by degree) -- needs rp from k_bfuse
    k_dcnt <<<128, 256, 0, stream>>>(i_rp, i_dcnt, N);
    k_dscan<<<1, 256, 0, stream>>>(i_dcnt, i_dcur);
    k_dbin <<<(N+2047)/2048, 256, 0, stream>>>(i_rp, i_dcur, i_dperm, N);

    int ga = 4096;
    int gg = 768;
    // conv0: GAT(x, W0)
    k_gemm<<<gg, 256, 0, stream>>>(x, nullptr, nullptr, hb, Wf3, waf3, Hw, f_as, f_ad, N);
    k_agg <<<ga, 256, 0, stream>>>(Hw, f_as, f_ad, i_rp, i_col, i_dperm, b0, outb, N);
    // conv1: GAT(out0 + vn_emb, Wl[0])
    k_gemm<<<gg, 256, 0, stream>>>(outb, vne, nullptr, hb, Wf3 + 512, waf3 + 2048, Hw, f_as, f_ad, N);
    k_agg <<<ga, 256, 0, stream>>>(Hw, f_as, f_ad, i_rp, i_col, i_dperm, bl, outb, N);
    // vn update: vnD = MLPs(segsum(out1) + 2*vne)  -- grouped register sum
    k_vsum<<<HNUM*8, 256, 0, stream>>>(outb, i_perm, i_vrp, f_vnS);
    k_vn  <<<HNUM, 64, 0, stream>>>(f_vnS, vne, mW1, mb1, mW2, mb2, f_vnD);
    // conv2: GAT(out1 + vnD[hb], Wl[1]) -> final output
    k_gemm<<<gg, 256, 0, stream>>>(outb, nullptr, f_vnD, hb, Wf3 + 1024, waf3 + 4096, Hw, f_as, f_ad, N);
    k_agg <<<ga, 256, 0, stream>>>(Hw, f_as, f_ad, i_rp, i_col, i_dperm, bl + HD, outb, N);
}

// Round 16
// 243.200 us; speedup vs baseline: 1.0636x; 1.0636x over previous
//
#include <hip/hip_runtime.h>
#include <hip/hip_fp16.h>
#include <math.h>

#define HD 64
#define HNUM 128
#define NMLP 2
#define BSH 8              // 256 dst-nodes per bucket
#define MAXNB 512
#define EPB 4096           // edges per k_bin block (16/thread)

typedef unsigned int uint_t;
typedef unsigned short ushort_t;
typedef _Float16 h8 __attribute__((ext_vector_type(8)));
typedef float vf4 __attribute__((ext_vector_type(4)));

union H8U { h8 v; uint_t u[4]; };
union H4  { uint2 u; _Float16 h[4]; };   // fp16 quad view -> enables v_fma_mix fusion

__device__ __forceinline__ float lrelu(float x){ return fmaxf(x, 0.2f*x); }

__device__ __forceinline__ uint_t pk2(float a, float b){
    return (uint_t)__half_as_ushort(__float2half_rn(a)) |
           ((uint_t)__half_as_ushort(__float2half_rn(b)) << 16);
}

// ---------------- CSR build: bucketed counting sort (packed 4B records) ----------------
__global__ __launch_bounds__(256) void k_bcnt(const int* __restrict__ dst, int* __restrict__ gb,
                                              int E, int NB){
    __shared__ int h[MAXNB];
    int t = threadIdx.x;
    for(int i=t;i<NB;i+=256) h[i] = 0;
    __syncthreads();
    for(int e = blockIdx.x*256 + t; e < E; e += gridDim.x*256)
        atomicAdd(&h[dst[e]>>BSH], 1);
    __syncthreads();
    for(int i=t;i<NB;i+=256) if(h[i]) atomicAdd(&gb[i], h[i]);
}

__global__ __launch_bounds__(512) void k_bscan(const int* __restrict__ gb, int* __restrict__ bbase,
                                               int* __restrict__ gcur, int NB){
    __shared__ int s[512];
    int t = threadIdx.x;
    int v = (t < NB) ? gb[t] : 0;
    s[t] = v; __syncthreads();
    for(int o=1;o<512;o<<=1){
        int u = (t >= o) ? s[t-o] : 0;
        __syncthreads();
        s[t] += u;
        __syncthreads();
    }
    if(t < NB){ int ex = s[t] - v; bbase[t] = ex; gcur[t] = ex; }
}

__global__ __launch_bounds__(256) void k_bin(const int* __restrict__ src, const int* __restrict__ dst,
                                             int* __restrict__ gcur, uint_t* __restrict__ bdata,
                                             int E, int NB){
    __shared__ int cnt[MAXNB];
    __shared__ int base[MAXNB];
    int t = threadIdx.x;
    for(int i=t;i<NB;i+=256) cnt[i] = 0;
    __syncthreads();
    int s0 = blockIdx.x*EPB;
    uint_t pk[16]; int bk[16], off[16];
    #pragma unroll
    for(int i=0;i<16;i++){
        int e = s0 + i*256 + t;
        if(e < E){
            int sv = src[e], dv = dst[e];
            pk[i]  = ((uint_t)sv << 8) | (uint_t)(dv & 255);
            bk[i]  = dv >> BSH;
            off[i] = atomicAdd(&cnt[bk[i]], 1);
        }
    }
    __syncthreads();
    for(int i=t;i<NB;i+=256) base[i] = cnt[i] ? atomicAdd(&gcur[i], cnt[i]) : 0;
    __syncthreads();
    #pragma unroll
    for(int i=0;i<16;i++){
        int e = s0 + i*256 + t;
        if(e < E) bdata[base[bk[i]] + off[i]] = pk[i];
    }
}

// fused per-bucket: LDS hist -> LDS scan -> rowptr slice -> LDS-cursor scatter
__global__ __launch_bounds__(256) void k_bfuse(const uint_t* __restrict__ bdata, const int* __restrict__ bbase,
                                               const int* __restrict__ gb, int* __restrict__ rp,
                                               int* __restrict__ col, int n, int NB, int E){
    __shared__ int h[256];
    __shared__ int sc[256];
    int b = blockIdx.x, t = threadIdx.x;
    int beg = bbase[b], cnt = gb[b];
    h[t] = 0; __syncthreads();
    for(int i=t;i<cnt;i+=256) atomicAdd(&h[bdata[beg+i] & 255], 1);
    __syncthreads();
    int v = h[t];
    sc[t] = v; __syncthreads();
    for(int o=1;o<256;o<<=1){
        int u = (t >= o) ? sc[t-o] : 0;
        __syncthreads();
        sc[t] += u;
        __syncthreads();
    }
    int excl = sc[t] - v;
    int node = (b<<BSH) + t;
    if(node < n) rp[node] = beg + excl;
    if(b == NB-1 && t == 255) rp[n] = E;
    __syncthreads();
    sc[t] = excl;           // per-node local cursor
    __syncthreads();
    for(int i=t;i<cnt;i+=256){
        uint_t e = bdata[beg+i];
        int pos = atomicAdd(&sc[e & 255], 1);
        col[beg + pos] = (int)(e >> 8);
    }
}

// ---------------- vn-group build: counting sort of nodes by hb ----------------
__global__ __launch_bounds__(256) void k_vcnt(const int* __restrict__ hb, int* __restrict__ vcnt, int n){
    __shared__ int h[HNUM];
    int t = threadIdx.x;
    if(t < HNUM) h[t] = 0;
    __syncthreads();
    for(int i = blockIdx.x*256 + t; i < n; i += gridDim.x*256) atomicAdd(&h[hb[i]], 1);
    __syncthreads();
    if(t < HNUM && h[t]) atomicAdd(&vcnt[t], h[t]);
}

__global__ __launch_bounds__(128) void k_vscan(const int* __restrict__ vcnt, int* __restrict__ vrp,
                                               int* __restrict__ vcur, int n){
    __shared__ int s[HNUM];
    int t = threadIdx.x;
    int v = vcnt[t];
    s[t] = v; __syncthreads();
    for(int o=1;o<HNUM;o<<=1){
        int u = (t >= o) ? s[t-o] : 0;
        __syncthreads();
        s[t] += u;
        __syncthreads();
    }
    int ex = s[t] - v;
    vrp[t] = ex; vcur[t] = ex;
    if(t == HNUM-1) vrp[HNUM] = n;
}

__global__ __launch_bounds__(256) void k_vbin(const int* __restrict__ hb, int* __restrict__ vcur,
                                              int* __restrict__ perm, int n){
    __shared__ int cnt[HNUM];
    __shared__ int base[HNUM];
    int t = threadIdx.x;
    if(t < HNUM) cnt[t] = 0;
    __syncthreads();
    int s0 = blockIdx.x*2048;
    int hv[8], off[8];
    #pragma unroll
    for(int i=0;i<8;i++){
        int nd = s0 + i*256 + t;
        if(nd < n){ hv[i] = hb[nd]; off[i] = atomicAdd(&cnt[hv[i]], 1); }
    }
    __syncthreads();
    if(t < HNUM) base[t] = cnt[t] ? atomicAdd(&vcur[t], cnt[t]) : 0;
    __syncthreads();
    #pragma unroll
    for(int i=0;i<8;i++){
        int nd = s0 + i*256 + t;
        if(nd < n) perm[base[hv[i]] + off[i]] = nd;
    }
}

// ---------------- one-time weight fragment pack + W@a precompute ----------------
__global__ __launch_bounds__(256) void k_wcvt(
    const float* __restrict__ W0, const float* __restrict__ as0, const float* __restrict__ ad0,
    const float* __restrict__ Wl, const float* __restrict__ asl, const float* __restrict__ adl,
    uint4* __restrict__ Wf3, float* __restrict__ waf3)
{
    __shared__ float wa[2][64];
    int L = blockIdx.x, t = threadIdx.x;
    const float* W  = (L==0) ? W0  : Wl  + (L-1)*HD*HD;
    const float* as = (L==0) ? as0 : asl + (L-1)*HD;
    const float* ad = (L==0) ? ad0 : adl + (L-1)*HD;
    if(t < 128){
        int sd = t>>6, k = t&63;
        const float* av = sd ? ad : as;
        float acc = 0.f;
        for(int c=0;c<HD;c++) acc = fmaf(W[k*HD+c], av[c], acc);
        wa[sd][k] = acc;
    }
    __syncthreads();
    for(int it = t; it < 512; it += 256){
        int lane = it&63, s = (it>>6)&1, tile = it>>7;
        int g = lane>>4, m = lane&15, c = tile*16 + m;
        ushort_t h[8];
        #pragma unroll
        for(int i=0;i<8;i++){
            int k = s*32 + g*4 + (i&3) + 16*(i>>2);
            h[i] = __half_as_ushort(__float2half_rn(W[k*HD + c]));
        }
        uint4 q;
        q.x = (uint_t)h[0] | ((uint_t)h[1]<<16);
        q.y = (uint_t)h[2] | ((uint_t)h[3]<<16);
        q.z = (uint_t)h[4] | ((uint_t)h[5]<<16);
        q.w = (uint_t)h[6] | ((uint_t)h[7]<<16);
        Wf3[(size_t)L*512 + (tile*2+s)*64 + lane] = q;
    }
    if(t < 128){
        int lane = t&63, sd = t>>6, g = lane>>4;
        #pragma unroll
        for(int j4=0;j4<4;j4++){
            float v[4];
            #pragma unroll
            for(int e=0;e<4;e++){
                int j = j4*4 + e;
                int k = (j>>3)*32 + g*4 + (j&3) + 16*((j>>2)&1);
                v[e] = wa[sd][k];
            }
            float* dstp = waf3 + ((size_t)L*8 + sd*4 + j4)*64*4 + lane*4;
            dstp[0]=v[0]; dstp[1]=v[1]; dstp[2]=v[2]; dstp[3]=v[3];
        }
    }
}

// ---------------- MFMA GEMM: 16 rows x 64 cols per wave ----------------
// Hw pair-layout: row dword w holds fp16 cols (32*(w>>4)+(w&15), same+16)
__global__ __launch_bounds__(256) void k_gemm(
    const float* __restrict__ IN, const float* __restrict__ addrow,
    const float* __restrict__ addtab, const int* __restrict__ hb,
    const uint4* __restrict__ Wf, const float* __restrict__ waf,
    uint_t* __restrict__ Hw, float* __restrict__ AS, float* __restrict__ AD,
    int n)
{
    __shared__ ushort_t sx[4][1024];
    int t = threadIdx.x, lane = t&63, wv = t>>6;
    int g = lane>>4, m = lane&15;
    ushort_t* sb = sx[wv];

    H8U B[8];
    #pragma unroll
    for(int f=0; f<8; f++){
        uint4 q = Wf[f*64 + lane];
        B[f].u[0]=q.x; B[f].u[1]=q.y; B[f].u[2]=q.z; B[f].u[3]=q.w;
    }
    vf4 wS[4], wD[4];
    #pragma unroll
    for(int j4=0;j4<4;j4++){
        const float* ps = waf + ((size_t)0*4 + j4)*256 + lane*4;
        const float* pd = waf + ((size_t)1*4 + j4)*256 + lane*4;
        wS[j4] = vf4{ps[0],ps[1],ps[2],ps[3]};
        wD[j4] = vf4{pd[0],pd[1],pd[2],pd[3]};
    }
    float ar0=0,ar1=0,ar2=0,ar3=0;
    if(addrow){
        const float* a = &addrow[m*4];
        ar0=a[0]; ar1=a[1]; ar2=a[2]; ar3=a[3];
    }

    int ntiles = (n + 15) >> 4;
    int wgid = (blockIdx.x*256 + t) >> 6;
    int nw = gridDim.x*4;
    for(int tile = wgid; tile < ntiles; tile += nw){
        int rb = tile*16;
        #pragma unroll
        for(int p=0;p<4;p++){
            int row = p*4 + g;
            int rowc = min(rb + row, n-1);
            float4 x4 = *(const float4*)&IN[(size_t)rowc*HD + m*4];
            if(addrow){ x4.x+=ar0; x4.y+=ar1; x4.z+=ar2; x4.w+=ar3; }
            if(addtab){
                int b = hb[rowc];
                float4 a4 = *(const float4*)&addtab[b*HD + m*4];
                x4.x+=a4.x; x4.y+=a4.y; x4.z+=a4.z; x4.w+=a4.w;
            }
            uint2 pq; pq.x = pk2(x4.x, x4.y); pq.y = pk2(x4.z, x4.w);
            int idx = (row*64 + m*4) ^ ((row&7)<<3);
            *(uint2*)&sb[idx] = pq;
        }
        int xr = (m&7)<<3;
        H8U A0, A1;
        {
            uint2 c0 = *(uint2*)&sb[(m*64 +  0 + g*4) ^ xr];
            uint2 c1 = *(uint2*)&sb[(m*64 + 16 + g*4) ^ xr];
            A0.u[0]=c0.x; A0.u[1]=c0.y; A0.u[2]=c1.x; A0.u[3]=c1.y;
            uint2 c2 = *(uint2*)&sb[(m*64 + 32 + g*4) ^ xr];
            uint2 c3 = *(uint2*)&sb[(m*64 + 48 + g*4) ^ xr];
            A1.u[0]=c2.x; A1.u[1]=c2.y; A1.u[2]=c3.x; A1.u[3]=c3.y;
        }
        float t1 = 0.f, t2 = 0.f;
        #pragma unroll
        for(int i=0;i<8;i++){
            float xv = (float)A0.v[i];
            t1 = fmaf(xv, wS[i>>2][i&3], t1);
            t2 = fmaf(xv, wD[i>>2][i&3], t2);
        }
        #pragma unroll
        for(int i=0;i<8;i++){
            float xv = (float)A1.v[i];
            t1 = fmaf(xv, wS[2+(i>>2)][i&3], t1);
            t2 = fmaf(xv, wD[2+(i>>2)][i&3], t2);
        }
        t1 += __shfl_xor(t1, 16, 64); t1 += __shfl_xor(t1, 32, 64);
        t2 += __shfl_xor(t2, 16, 64); t2 += __shfl_xor(t2, 32, 64);
        if(lane < 16 && rb + lane < n){ AS[rb+lane] = t1; AD[rb+lane] = t2; }
        vf4 z = {0.f,0.f,0.f,0.f};
        vf4 a0 = __builtin_amdgcn_mfma_f32_16x16x32_f16(A0.v, B[0].v, z, 0,0,0);
        a0     = __builtin_amdgcn_mfma_f32_16x16x32_f16(A1.v, B[1].v, a0, 0,0,0);
        vf4 a1 = __builtin_amdgcn_mfma_f32_16x16x32_f16(A0.v, B[2].v, z, 0,0,0);
        a1     = __builtin_amdgcn_mfma_f32_16x16x32_f16(A1.v, B[3].v, a1, 0,0,0);
        vf4 a2 = __builtin_amdgcn_mfma_f32_16x16x32_f16(A0.v, B[4].v, z, 0,0,0);
        a2     = __builtin_amdgcn_mfma_f32_16x16x32_f16(A1.v, B[5].v, a2, 0,0,0);
        vf4 a3 = __builtin_amdgcn_mfma_f32_16x16x32_f16(A0.v, B[6].v, z, 0,0,0);
        a3     = __builtin_amdgcn_mfma_f32_16x16x32_f16(A1.v, B[7].v, a3, 0,0,0);
        #pragma unroll
        for(int rr=0;rr<4;rr++){
            int row = rb + g*4 + rr;
            if(row < n){
                Hw[(size_t)row*32 + m]      = pk2(a0[rr], a1[rr]);
                Hw[(size_t)row*32 + 16 + m] = pk2(a2[rr], a3[rr]);
            }
        }
    }
}

// ---------------- GAT aggregate: quarter-wave per dst (4 dsts/wave), fma_mix-friendly ----------------
__global__ __launch_bounds__(256) void k_agg(
    const uint_t* __restrict__ Hb, const float* __restrict__ AS, const float* __restrict__ AD,
    const int* __restrict__ rp, const int* __restrict__ col,
    const float* __restrict__ bias, float* __restrict__ OUT, int n)
{
    int t = threadIdx.x, lane = t & 63;
    int p = lane & 15;          // position within quarter
    int qb = lane & 48;         // quarter base lane (0,16,32,48)
    int w0 = 2*p;
    int c00 = 32*(w0>>4)+(w0&15), c01 = c00+16;
    int c10 = c00+1, c11 = c00+17;
    float b00 = bias[c00], b01 = bias[c01], b10 = bias[c10], b11 = bias[c11];
    int wv  = (blockIdx.x*256 + t) >> 6;
    int nwv = gridDim.x*4;
    for(int base = wv*4; base < n; base += nwv*4){
        int dq = min(base + (qb>>4), n-1);
        float ad = AD[dq];
        float wself = __expf(lrelu(AS[dq] + ad));
        H4 hd; hd.u = *(const uint2*)&Hb[(size_t)dq*32 + w0];
        float4 acc;
        acc.x = (float)hd.h[0]*wself; acc.y = (float)hd.h[1]*wself;
        acc.z = (float)hd.h[2]*wself; acc.w = (float)hd.h[3]*wself;
        float sacc = 0.f;
        int beg = rp[dq], end = rp[dq+1];
        int cnt = end - beg;
        int nit = (cnt + 15) >> 4;
        nit = max(nit, __shfl_xor(nit, 16, 64));
        nit = max(nit, __shfl_xor(nit, 32, 64));
        for(int it = 0; it < nit; it++){
            int j = beg + it*16 + p;
            bool valid = j < end;
            int sj = dq;
            if(cnt > 0) sj = col[valid ? j : end - 1];
            float wj = 0.f;
            if(valid) wj = __expf(lrelu(AS[sj] + ad));
            sacc += wj;
            int ccnt = cnt - it*16;
            ccnt = ccnt < 0 ? 0 : (ccnt > 16 ? 16 : ccnt);
            int emax = ccnt;
            emax = max(emax, __shfl_xor(emax, 16, 64));
            emax = max(emax, __shfl_xor(emax, 32, 64));
            int e = 0;
            for(; e + 4 <= emax; e += 4){
                float wq0 = __shfl(wj, qb+e,   64);
                float wq1 = __shfl(wj, qb+e+1, 64);
                float wq2 = __shfl(wj, qb+e+2, 64);
                float wq3 = __shfl(wj, qb+e+3, 64);
                int   sq0 = __shfl(sj, qb+e,   64);
                int   sq1 = __shfl(sj, qb+e+1, 64);
                int   sq2 = __shfl(sj, qb+e+2, 64);
                int   sq3 = __shfl(sj, qb+e+3, 64);
                H4 v0; v0.u = *(const uint2*)&Hb[(size_t)sq0*32 + w0];
                H4 v1; v1.u = *(const uint2*)&Hb[(size_t)sq1*32 + w0];
                H4 v2; v2.u = *(const uint2*)&Hb[(size_t)sq2*32 + w0];
                H4 v3; v3.u = *(const uint2*)&Hb[(size_t)sq3*32 + w0];
                acc.x = fmaf(wq0, (float)v0.h[0], acc.x);
                acc.y = fmaf(wq0, (float)v0.h[1], acc.y);
                acc.z = fmaf(wq0, (float)v0.h[2], acc.z);
                acc.w = fmaf(wq0, (float)v0.h[3], acc.w);
                acc.x = fmaf(wq1, (float)v1.h[0], acc.x);
                acc.y = fmaf(wq1, (float)v1.h[1], acc.y);
                acc.z = fmaf(wq1, (float)v1.h[2], acc.z);
                acc.w = fmaf(wq1, (float)v1.h[3], acc.w);
                acc.x = fmaf(wq2, (float)v2.h[0], acc.x);
                acc.y = fmaf(wq2, (float)v2.h[1], acc.y);
                acc.z = fmaf(wq2, (float)v2.h[2], acc.z);
                acc.w = fmaf(wq2, (float)v2.h[3], acc.w);
                acc.x = fmaf(wq3, (float)v3.h[0], acc.x);
                acc.y = fmaf(wq3, (float)v3.h[1], acc.y);
                acc.z = fmaf(wq3, (float)v3.h[2], acc.z);
                acc.w = fmaf(wq3, (float)v3.h[3], acc.w);
            }
            for(; e < emax; e++){
                float wq = __shfl(wj, qb+e, 64);
                int   sq = __shfl(sj, qb+e, 64);
                H4 v; v.u = *(const uint2*)&Hb[(size_t)sq*32 + w0];
                acc.x = fmaf(wq, (float)v.h[0], acc.x);
                acc.y = fmaf(wq, (float)v.h[1], acc.y);
                acc.z = fmaf(wq, (float)v.h[2], acc.z);
                acc.w = fmaf(wq, (float)v.h[3], acc.w);
            }
        }
        sacc += __shfl_xor(sacc, 1, 64);
        sacc += __shfl_xor(sacc, 2, 64);
        sacc += __shfl_xor(sacc, 4, 64);
        sacc += __shfl_xor(sacc, 8, 64);
        float s = wself + sacc;
        float inv = 1.f/(s + 1e-16f);
        if(base + (qb>>4) < n){
            OUT[(size_t)dq*HD + c00] = fmaf(acc.x, inv, b00);
            OUT[(size_t)dq*HD + c01] = fmaf(acc.y, inv, b01);
            OUT[(size_t)dq*HD + c10] = fmaf(acc.z, inv, b10);
            OUT[(size_t)dq*HD + c11] = fmaf(acc.w, inv, b11);
        }
    }
}

// ---------------- vn segment sum: hb-grouped, pure register accumulation ----------------
__global__ __launch_bounds__(256) void k_vsum(const float* __restrict__ OUT, const int* __restrict__ perm,
                                              const int* __restrict__ vrp, float* __restrict__ vnS){
    int t = threadIdx.x, lane = t & 63, w = t >> 6;
    int g = blockIdx.x >> 3, sub = blockIdx.x & 7;
    int wig = sub*4 + w;                  // wave index in group: 0..31
    int beg = vrp[g], end = vrp[g+1];
    float a0=0.f, a1=0.f, a2=0.f, a3=0.f;
    int i = beg + wig;
    for(; i + 96 < end; i += 128){
        int p0 = perm[i], p1 = perm[i+32], p2 = perm[i+64], p3 = perm[i+96];
        a0 += OUT[(size_t)p0*HD + lane];
        a1 += OUT[(size_t)p1*HD + lane];
        a2 += OUT[(size_t)p2*HD + lane];
        a3 += OUT[(size_t)p3*HD + lane];
    }
    for(; i < end; i += 32) a0 += OUT[(size_t)perm[i]*HD + lane];
    float a = (a0+a1)+(a2+a3);
    unsafeAtomicAdd(&vnS[g*HD + lane], a);   // 32 contenders per address
}

// ---------------- vn update: one wave per vn row; LDS-broadcast MLPs ----------------
__global__ __launch_bounds__(64) void k_vn(
    const float* __restrict__ vnS, const float* __restrict__ vne,
    const float* __restrict__ W1, const float* __restrict__ B1,
    const float* __restrict__ W2, const float* __restrict__ B2,
    float* __restrict__ vnD)
{
    __shared__ float sx[HD];
    int lane = threadIdx.x;
    int r = blockIdx.x;                 // vn row 0..HNUM-1
    float ve = vne[lane];
    float a = vnS[r*HD + lane] + ve + ve;   // segsum + vn_direct0 + vn_root0
    for(int j=0;j<NMLP;j++){
        const float* w1 = W1 + j*HD*HD; const float* b1 = B1 + j*HD;
        const float* w2 = W2 + j*HD*HD; const float* b2 = B2 + j*HD;
        __syncthreads();
        sx[lane] = a;
        __syncthreads();
        float t = b1[lane];
        #pragma unroll
        for(int in=0;in<HD;in++) t = fmaf(sx[in], w1[in*HD + lane], t);
        t = fmaxf(t, 0.f);
        __syncthreads();
        sx[lane] = t;
        __syncthreads();
        float u = b2[lane];
        #pragma unroll
        for(int in=0;in<HD;in++) u = fmaf(sx[in], w2[in*HD + lane], u);
        a = fmaxf(u, 0.f);
    }
    vnD[r*HD + lane] = a;
}

extern "C" void kernel_launch(void* const* d_in, const int* in_sizes, int n_in,
                              void* d_out, int out_size, void* d_ws, size_t ws_size,
                              hipStream_t stream)
{
    const float* x   = (const float*)d_in[0];
    const int*   ei  = (const int*)d_in[1];
    const int*   hb  = (const int*)d_in[2];
    const float* W0  = (const float*)d_in[5];
    const float* as0 = (const float*)d_in[6];
    const float* ad0 = (const float*)d_in[7];
    const float* b0  = (const float*)d_in[8];
    const float* Wl  = (const float*)d_in[9];
    const float* asl = (const float*)d_in[10];
    const float* adl = (const float*)d_in[11];
    const float* bl  = (const float*)d_in[12];
    const float* vne = (const float*)d_in[13];
    const float* mW1 = (const float*)d_in[14];
    const float* mb1 = (const float*)d_in[15];
    const float* mW2 = (const float*)d_in[16];
    const float* mb2 = (const float*)d_in[17];

    int N = in_sizes[0]/HD;
    int E = in_sizes[1]/2;
    const int* src = ei;
    const int* dst = ei + E;
    int NB = (N + (1<<BSH) - 1) >> BSH;

    char* p = (char*)d_ws;
    float* f_h   = (float*)p; p += (size_t)N*HD*4;   // fp16 H (lower half) + CSR alias
    float* f_as  = (float*)p; p += (size_t)N*4;
    float* f_ad  = (float*)p; p += (size_t)N*4;
    float* f_vnD = (float*)p; p += HNUM*HD*4;
    float* f_vnS = (float*)p; p += HNUM*HD*4;        // zeroed with i_vcnt below
    int*   i_vcnt= (int*)p;   p += HNUM*4;
    int*   i_vrp = (int*)p;   p += (HNUM+1)*4;
    int*   i_vcur= (int*)p;   p += HNUM*4;
    int*   i_perm= (int*)p;   p += (size_t)N*4;
    int*   i_rp  = (int*)p;   p += (size_t)(N+1)*4;
    int*   i_gb  = (int*)p;   p += MAXNB*4;
    int*   i_bb  = (int*)p;   p += MAXNB*4;
    int*   i_gc  = (int*)p;   p += MAXNB*4;
    int*   i_col = (int*)p;   p += (size_t)E*4;
    uint4* Wf3   = (uint4*)p; p += 3*512*16;
    float* waf3  = (float*)p; p += 3*8*64*4*4;
    uint_t* bdata= (uint_t*)f_h;                      // alias: f_h not live during CSR build
    uint_t* Hw   = (uint_t*)f_h;                      // N*32 dwords = lower 12.8 MB

    float* outb = (float*)d_out;

    // one-time weight pack (3 blocks = 3 layers)
    k_wcvt<<<3, 256, 0, stream>>>(W0, as0, ad0, Wl, asl, adl, Wf3, waf3);

    hipMemsetAsync(i_gb, 0, MAXNB*4, stream);
    hipMemsetAsync(f_vnS, 0, HNUM*HD*4 + HNUM*4, stream);   // vnS + vcnt
    // edge CSR
    k_bcnt <<<512, 256, 0, stream>>>(dst, i_gb, E, NB);
    k_bscan<<<1, 512, 0, stream>>>(i_gb, i_bb, i_gc, NB);
    k_bin  <<<(E+EPB-1)/EPB, 256, 0, stream>>>(src, dst, i_gc, bdata, E, NB);
    k_bfuse<<<NB, 256, 0, stream>>>(bdata, i_bb, i_gb, i_rp, i_col, N, NB, E);
    // vn-group permutation (counting sort of nodes by hb)
    k_vcnt <<<128, 256, 0, stream>>>(hb, i_vcnt, N);
    k_vscan<<<1, 128, 0, stream>>>(i_vcnt, i_vrp, i_vcur, N);
    k_vbin <<<(N+2047)/2048, 256, 0, stream>>>(hb, i_vcur, i_perm, N);

    int ga = 4096;
    int gg = 768;
    // conv0: GAT(x, W0)
    k_gemm<<<gg, 256, 0, stream>>>(x, nullptr, nullptr, hb, Wf3, waf3, Hw, f_as, f_ad, N);
    k_agg <<<ga, 256, 0, stream>>>(Hw, f_as, f_ad, i_rp, i_col, b0, outb, N);
    // conv1: GAT(out0 + vn_emb, Wl[0])
    k_gemm<<<gg, 256, 0, stream>>>(outb, vne, nullptr, hb, Wf3 + 512, waf3 + 2048, Hw, f_as, f_ad, N);
    k_agg <<<ga, 256, 0, stream>>>(Hw, f_as, f_ad, i_rp, i_col, bl, outb, N);
    // vn update: vnD = MLPs(segsum(out1) + 2*vne)  -- grouped register sum
    k_vsum<<<HNUM*8, 256, 0, stream>>>(outb, i_perm, i_vrp, f_vnS);
    k_vn  <<<HNUM, 64, 0, stream>>>(f_vnS, vne, mW1, mb1, mW2, mb2, f_vnD);
    // conv2: GAT(out1 + vnD[hb], Wl[1]) -> final output
    k_gemm<<<gg, 256, 0, stream>>>(outb, nullptr, f_vnD, hb, Wf3 + 1024, waf3 + 4096, Hw, f_as, f_ad, N);
    k_agg <<<ga, 256, 0, stream>>>(Hw, f_as, f_ad, i_rp, i_col, bl + HD, outb, N);
}